// Round 3
// baseline (119.232 us; speedup 1.0000x reference)
//
#include <hip/hip_runtime.h>
#include <hip/hip_bf16.h>

// Problem constants (fixed by the reference)
#define NB   8
#define C    128
#define H    112
#define W    112
#define HW   (H * W)
#define HO   56
#define WO   56
#define KK   9      // 3x3 = 9 sigma channels
#define WAVES 16
#define CPW  8      // channels per wave = C / WAVES
#define NPAIR (C / 2)            // 64 channel pairs
#define WPK_ELEMS (NPAIR * 81)   // float2 count: [cip][kh][k*3+kw]
#define SHIFT_OFF (WPK_ELEMS * 2)  // float offset of shift[9] in ws

// ---------------------------------------------------------------------------
// Kernel 0: weights -> d_ws as channel-PAIR packed float2, BN scale folded.
// layout: wpk[cip][kh][k*3+kw] = (w[2cip], w[2cip+1]); then shift[9].
// ---------------------------------------------------------------------------
__global__ void pasa_prep(const float* __restrict__ cw,
                          const float* __restrict__ bw,
                          const float* __restrict__ bb,
                          const float* __restrict__ bm,
                          const float* __restrict__ bv,
                          float* __restrict__ ws) {
    int idx = blockIdx.x * 256 + threadIdx.x;
    if (idx < WPK_ELEMS) {
        int cip = idx / 81;
        int rem = idx % 81;
        int kh = rem / 27;
        int r2 = rem % 27;
        int k  = r2 / 3;
        int kw = r2 % 3;
        float scale = bw[k] / sqrtf(bv[k] + 1e-5f);
        int ca = 2 * cip, cb = 2 * cip + 1;
        ws[2 * idx + 0] = cw[((k * C + ca) * 3 + kh) * 3 + kw] * scale;
        ws[2 * idx + 1] = cw[((k * C + cb) * 3 + kh) * 3 + kw] * scale;
    } else if (idx < WPK_ELEMS + KK) {
        int k = idx - WPK_ELEMS;
        float scale = bw[k] / sqrtf(bv[k] + 1e-5f);
        ws[SHIFT_OFF + k] = bb[k] - bm[k] * scale;
    }
}

__device__ inline float2 pkfma(float2 a, float2 b, float2 c) {
    float2 r;
    r.x = fmaf(a.x, b.x, c.x);
    r.y = fmaf(a.y, b.y, c.y);
    return r;
}

// ---------------------------------------------------------------------------
// Kernel 1: fused PASA downsample. One block per (n, ho) output row.
// Weights via __restrict__ arg + wave-uniform index -> s_load + SGPR-operand
// FMA (no per-lane weight VMEM). Channel-pair packed accumulation.
// ---------------------------------------------------------------------------
__global__ __launch_bounds__(1024, 8)
void pasa_main(const float* __restrict__ x,
               const float2* __restrict__ wpk,
               const float* __restrict__ shift,
               float* __restrict__ out) {
    __shared__ float part[WAVES * KK * 64];   // 36 KB
    __shared__ float sig[KK * 57];            // padded row stride

    // XCD swizzle: grid 448 = 8 XCDs * 56 rows; physical bid%8 = XCD.
    const int bid  = blockIdx.x;
    const int n    = bid & 7;
    const int ho   = bid >> 3;
    const int tid  = threadIdx.x;
    const int lane = tid & 63;
    const int wv   = __builtin_amdgcn_readfirstlane(tid >> 6);  // wave-uniform
    const int wo   = lane < WO ? lane : (WO - 1);               // clamp tail

    // Reflection-resolved source rows (top reflect only: -1 -> 1).
    int rows[3];
    rows[0] = (ho == 0) ? 1 : (2 * ho - 1);
    rows[1] = 2 * ho;
    rows[2] = 2 * ho + 1;

    const float* xn = x + (size_t)n * C * HW;

    // ---- Phase A: packed partial sigma over this wave's 4 channel pairs ---
    float2 acc[KK];
#pragma unroll
    for (int k = 0; k < KK; ++k) acc[k] = make_float2(0.0f, 0.0f);

    const int p0 = wv * (CPW / 2);   // first pair of this wave

    auto ldpair = [&](int cip, float2* a, float2* b) {
        const float* xa = xn + (size_t)(2 * cip) * HW;
        const float* xb = xa + HW;
#pragma unroll
        for (int kh = 0; kh < 3; ++kh) {
            a[kh] = *(const float2*)(xa + rows[kh] * W + 2 * wo);
            b[kh] = *(const float2*)(xb + rows[kh] * W + 2 * wo);
        }
    };
    auto consume = [&](const float2* a, const float2* b, const float2* wb) {
#pragma unroll
        for (int kh = 0; kh < 3; ++kh) {
            float2 t1 = make_float2(a[kh].x, b[kh].x);
            float2 t2 = make_float2(a[kh].y, b[kh].y);
            float2 t0;
            t0.x = __shfl_up(t2.x, 1);   // lane0 keeps own = reflect(-1)=col1
            t0.y = __shfl_up(t2.y, 1);
            const float2* wr = wb + kh * 27;   // wave-uniform -> s_load
#pragma unroll
            for (int k = 0; k < KK; ++k)
                acc[k] = pkfma(t2, wr[3 * k + 2],
                          pkfma(t1, wr[3 * k + 1],
                          pkfma(t0, wr[3 * k + 0], acc[k])));
        }
    };

    {
        float2 a0[3], b0[3];
        ldpair(p0, a0, b0);
        for (int p = 0; p < CPW / 2; ++p) {
            float2 a1[3], b1[3];
            if (p + 1 < CPW / 2) ldpair(p0 + p + 1, a1, b1);
            consume(a0, b0, wpk + (p0 + p) * 81);
#pragma unroll
            for (int kh = 0; kh < 3; ++kh) { a0[kh] = a1[kh]; b0[kh] = b1[kh]; }
        }
    }

#pragma unroll
    for (int k = 0; k < KK; ++k)
        part[(wv * KK + k) * 64 + lane] = acc[k].x + acc[k].y;
    __syncthreads();

    // ---- Cross-wave reduce + BN shift + clamp -----------------------------
    if (tid < KK * WO) {
        const int k = tid / WO;
        const int w_ = tid % WO;
        float s = 0.0f;
#pragma unroll
        for (int w2 = 0; w2 < WAVES; ++w2) s += part[(w2 * KK + k) * 64 + w_];
        s += shift[k];
        s = fmaxf(s, 1e-4f);
        sig[k * 57 + w_] = s;
    }
    __syncthreads();

    // ---- Normalize into registers (per-lane, lane = wo) -------------------
    float sg[KK];
    float tot = 0.0f;
#pragma unroll
    for (int k = 0; k < KK; ++k) { sg[k] = sig[k * 57 + wo]; tot += sg[k]; }
    const float inv = 1.0f / tot;
#pragma unroll
    for (int k = 0; k < KK; ++k) sg[k] *= inv;

    // ---- Phase B: apply adaptive filter (rows L1/L2-hot from Phase A) -----
    float* on = out + ((size_t)n * C) * (HO * WO) + ho * WO;
    auto apply1 = [&](const float2* v) {
        float o = 0.0f;
#pragma unroll
        for (int kh = 0; kh < 3; ++kh) {
            const float t1 = v[kh].x;
            const float t2 = v[kh].y;
            const float t0 = __shfl_up(t2, 1);
            o = fmaf(t0, sg[kh * 3 + 0],
                fmaf(t1, sg[kh * 3 + 1],
                fmaf(t2, sg[kh * 3 + 2], o)));
        }
        return o;
    };
    {
        float2 a0[3], b0[3];
        ldpair(p0, a0, b0);
        for (int p = 0; p < CPW / 2; ++p) {
            float2 a1[3], b1[3];
            if (p + 1 < CPW / 2) ldpair(p0 + p + 1, a1, b1);
            const float oa = apply1(a0);
            const float ob = apply1(b0);
            if (lane < WO) {
                const int ci = 2 * (p0 + p);
                on[(size_t)ci * (HO * WO) + lane]       = oa;
                on[(size_t)(ci + 1) * (HO * WO) + lane] = ob;
            }
#pragma unroll
            for (int kh = 0; kh < 3; ++kh) { a0[kh] = a1[kh]; b0[kh] = b1[kh]; }
        }
    }
}

extern "C" void kernel_launch(void* const* d_in, const int* in_sizes, int n_in,
                              void* d_out, int out_size, void* d_ws, size_t ws_size,
                              hipStream_t stream) {
    const float* x   = (const float*)d_in[0];
    const float* cw  = (const float*)d_in[1];
    const float* bw  = (const float*)d_in[2];
    const float* bb  = (const float*)d_in[3];
    const float* bm  = (const float*)d_in[4];
    const float* bv  = (const float*)d_in[5];
    float* ws  = (float*)d_ws;
    float* out = (float*)d_out;

    const int prep_elems = WPK_ELEMS + KK;
    pasa_prep<<<(prep_elems + 255) / 256, 256, 0, stream>>>(cw, bw, bb, bm, bv, ws);
    pasa_main<<<NB * HO, 1024, 0, stream>>>(x, (const float2*)ws,
                                            ws + SHIFT_OFF, out);
}

// Round 4
// 110.387 us; speedup vs baseline: 1.0801x; 1.0801x over previous
//
#include <hip/hip_runtime.h>
#include <hip/hip_bf16.h>

// Problem constants (fixed by the reference)
#define NB   8
#define C    128
#define H    112
#define W    112
#define HW   (H * W)
#define HO   56
#define WO   56
#define KK   9      // 3x3 = 9 sigma channels
#define WAVES 16
#define CPW  8      // channels per wave = C / WAVES
#define NPAIR (C / 2)            // 64 channel pairs
#define PPW  (CPW / 2)           // 4 pairs per wave
#define WPK_ELEMS (NPAIR * 81)   // float2 count: [cip][kh][k*3+kw]
#define SHIFT_OFF (WPK_ELEMS * 2)  // float offset of shift[9] in ws

// ---------------------------------------------------------------------------
// Kernel 0: weights -> d_ws as channel-PAIR packed float2, BN scale folded.
// ---------------------------------------------------------------------------
__global__ void pasa_prep(const float* __restrict__ cw,
                          const float* __restrict__ bw,
                          const float* __restrict__ bb,
                          const float* __restrict__ bm,
                          const float* __restrict__ bv,
                          float* __restrict__ ws) {
    int idx = blockIdx.x * 256 + threadIdx.x;
    if (idx < WPK_ELEMS) {
        int cip = idx / 81;
        int rem = idx % 81;
        int kh = rem / 27;
        int r2 = rem % 27;
        int k  = r2 / 3;
        int kw = r2 % 3;
        float scale = bw[k] / sqrtf(bv[k] + 1e-5f);
        int ca = 2 * cip, cb = 2 * cip + 1;
        ws[2 * idx + 0] = cw[((k * C + ca) * 3 + kh) * 3 + kw] * scale;
        ws[2 * idx + 1] = cw[((k * C + cb) * 3 + kh) * 3 + kw] * scale;
    } else if (idx < WPK_ELEMS + KK) {
        int k = idx - WPK_ELEMS;
        float scale = bw[k] / sqrtf(bv[k] + 1e-5f);
        ws[SHIFT_OFF + k] = bb[k] - bm[k] * scale;
    }
}

__device__ inline float2 pkfma(float2 a, float2 b, float2 c) {
    float2 r;
    r.x = fmaf(a.x, b.x, c.x);
    r.y = fmaf(a.y, b.y, c.y);
    return r;
}

// ---------------------------------------------------------------------------
// Kernel 1: fused PASA downsample, register-resident x.
// One block per (n, ho) row; 16 waves; lane = wo. Each wave loads ALL of its
// 8 channels' 3 rows (24 float2/lane) up-front, keeps them live across the
// sigma reduction barrier, and Phase B applies the adaptive filter from
// registers -> x is read from HBM exactly once.
// __launch_bounds__(1024, 4): 1 block/CU, VGPR cap 128 (need ~100, no spill).
// ---------------------------------------------------------------------------
__global__ __launch_bounds__(1024, 4)
void pasa_main(const float* __restrict__ x,
               const float2* __restrict__ wpk,
               const float* __restrict__ shift,
               float* __restrict__ out) {
    __shared__ float part[WAVES * KK * 64];   // 36 KB
    __shared__ float sig[KK * 57];            // padded row stride

    // XCD swizzle: grid 448 = 8 XCDs * 56 rows; physical bid%8 = XCD.
    const int bid  = blockIdx.x;
    const int n    = bid & 7;
    const int ho   = bid >> 3;
    const int tid  = threadIdx.x;
    const int lane = tid & 63;
    const int wv   = __builtin_amdgcn_readfirstlane(tid >> 6);  // wave-uniform
    const int wo   = lane < WO ? lane : (WO - 1);               // clamp tail

    // Reflection-resolved source rows (top reflect only: -1 -> 1).
    int rows[3];
    rows[0] = (ho == 0) ? 1 : (2 * ho - 1);
    rows[1] = 2 * ho;
    rows[2] = 2 * ho + 1;

    const float* xn = x + (size_t)n * C * HW;
    const int p0 = wv * PPW;   // first channel-pair of this wave

    // ---- Load ALL rows for this wave's 8 channels (24 float2, one drain) --
    float2 va[PPW][3], vb[PPW][3];
#pragma unroll
    for (int p = 0; p < PPW; ++p) {
        const float* xa = xn + (size_t)(2 * (p0 + p)) * HW;
        const float* xb = xa + HW;
#pragma unroll
        for (int kh = 0; kh < 3; ++kh) {
            va[p][kh] = *(const float2*)(xa + rows[kh] * W + 2 * wo);
            vb[p][kh] = *(const float2*)(xb + rows[kh] * W + 2 * wo);
        }
    }

    // ---- Phase A: packed partial sigma over the 4 channel pairs -----------
    float2 acc[KK];
#pragma unroll
    for (int k = 0; k < KK; ++k) acc[k] = make_float2(0.0f, 0.0f);

#pragma unroll
    for (int p = 0; p < PPW; ++p) {
        const float2* wb = wpk + (p0 + p) * 81;   // wave-uniform
#pragma unroll
        for (int kh = 0; kh < 3; ++kh) {
            float2 t1 = make_float2(va[p][kh].x, vb[p][kh].x);
            float2 t2 = make_float2(va[p][kh].y, vb[p][kh].y);
            float2 t0;
            t0.x = __shfl_up(t2.x, 1);   // lane0 keeps own = reflect(-1)=col1
            t0.y = __shfl_up(t2.y, 1);
            const float2* wr = wb + kh * 27;
#pragma unroll
            for (int k = 0; k < KK; ++k)
                acc[k] = pkfma(t2, wr[3 * k + 2],
                          pkfma(t1, wr[3 * k + 1],
                          pkfma(t0, wr[3 * k + 0], acc[k])));
        }
    }

#pragma unroll
    for (int k = 0; k < KK; ++k)
        part[(wv * KK + k) * 64 + lane] = acc[k].x + acc[k].y;
    __syncthreads();

    // ---- Cross-wave reduce + BN shift + clamp -----------------------------
    if (tid < KK * WO) {
        const int k = tid / WO;
        const int w_ = tid % WO;
        float s = 0.0f;
#pragma unroll
        for (int w2 = 0; w2 < WAVES; ++w2) s += part[(w2 * KK + k) * 64 + w_];
        s += shift[k];
        s = fmaxf(s, 1e-4f);
        sig[k * 57 + w_] = s;
    }
    __syncthreads();

    // ---- Normalize into registers (per-lane, lane = wo) -------------------
    float sg[KK];
    float tot = 0.0f;
#pragma unroll
    for (int k = 0; k < KK; ++k) { sg[k] = sig[k * 57 + wo]; tot += sg[k]; }
    const float inv = 1.0f / tot;
#pragma unroll
    for (int k = 0; k < KK; ++k) sg[k] *= inv;

    // ---- Phase B: apply adaptive filter from REGISTERS (no global loads) --
    float* on = out + ((size_t)n * C) * (HO * WO) + ho * WO;
#pragma unroll
    for (int p = 0; p < PPW; ++p) {
        float oa = 0.0f, ob = 0.0f;
#pragma unroll
        for (int kh = 0; kh < 3; ++kh) {
            const float a1 = va[p][kh].x, a2 = va[p][kh].y;
            const float b1 = vb[p][kh].x, b2 = vb[p][kh].y;
            const float a0 = __shfl_up(a2, 1);
            const float b0 = __shfl_up(b2, 1);
            oa = fmaf(a0, sg[kh * 3 + 0],
                 fmaf(a1, sg[kh * 3 + 1],
                 fmaf(a2, sg[kh * 3 + 2], oa)));
            ob = fmaf(b0, sg[kh * 3 + 0],
                 fmaf(b1, sg[kh * 3 + 1],
                 fmaf(b2, sg[kh * 3 + 2], ob)));
        }
        if (lane < WO) {
            const int ci = 2 * (p0 + p);
            on[(size_t)ci * (HO * WO) + lane]       = oa;
            on[(size_t)(ci + 1) * (HO * WO) + lane] = ob;
        }
    }
}

extern "C" void kernel_launch(void* const* d_in, const int* in_sizes, int n_in,
                              void* d_out, int out_size, void* d_ws, size_t ws_size,
                              hipStream_t stream) {
    const float* x   = (const float*)d_in[0];
    const float* cw  = (const float*)d_in[1];
    const float* bw  = (const float*)d_in[2];
    const float* bb  = (const float*)d_in[3];
    const float* bm  = (const float*)d_in[4];
    const float* bv  = (const float*)d_in[5];
    float* ws  = (float*)d_ws;
    float* out = (float*)d_out;

    const int prep_elems = WPK_ELEMS + KK;
    pasa_prep<<<(prep_elems + 255) / 256, 256, 0, stream>>>(cw, bw, bb, bm, bv, ws);
    pasa_main<<<NB * HO, 1024, 0, stream>>>(x, (const float2*)ws,
                                            ws + SHIFT_OFF, out);
}